// Round 3
// baseline (400.530 us; speedup 1.0000x reference)
//
#include <hip/hip_runtime.h>

#define H 512
#define NSEG 64
#define CHUNK 256
#define QV (H / 4)   // 128 float4 per row

typedef float f4 __attribute__((ext_vector_type(4)));

__device__ __forceinline__ void ntstore4(f4* p, f4 v) {
    __builtin_nontemporal_store(v, p);
}

// ---------------------------------------------------------------------------
// k1: segment sum + counts. Forward streaming with PLAIN loads (allocate in
// L3 so k3 can reuse the resident tail). Fast path for single-segment blocks
// (>96% of blocks): branch-free, 4 accumulators, LDS cross-group reduce
// before one atomic flush per column. Slow path: run-length + atomic flush.
// ---------------------------------------------------------------------------
__global__ __launch_bounds__(512) void k_segsum(
    const f4* __restrict__ hv, const int* __restrict__ bid,
    float* __restrict__ seg_sum, int* __restrict__ counts)
{
    __shared__ int sb[CHUNK];
    __shared__ f4 sred[4][QV];
    const int base = blockIdx.x * CHUNK;
    const int tid  = threadIdx.x;
    if (tid < CHUNK) sb[tid] = bid[base + tid];
    __syncthreads();

    const int g = tid >> 7;    // row-group 0..3
    const int q = tid & 127;   // float4 column 0..127

    if (sb[0] == sb[CHUNK - 1]) {
        // ---- fast path: whole block in one segment ----
        const int seg = sb[0];
        const f4* p = hv + (size_t)(base + g) * QV + q;
        f4 a0 = (f4)(0.f), a1 = (f4)(0.f), a2 = (f4)(0.f), a3 = (f4)(0.f);
        for (int i = 0; i < 16; ++i) {
            const size_t o = (size_t)i * (16 * QV);
            const f4 v0 = p[o];
            const f4 v1 = p[o + 4 * QV];
            const f4 v2 = p[o + 8 * QV];
            const f4 v3 = p[o + 12 * QV];
            a0 += v0; a1 += v1; a2 += v2; a3 += v3;
        }
        sred[g][q] = (a0 + a1) + (a2 + a3);
        __syncthreads();
        if (g == 0) {
            const f4 t = sred[0][q] + sred[1][q] + sred[2][q] + sred[3][q];
            float* dst = seg_sum + seg * H + q * 4;
            atomicAdd(dst + 0, t[0]); atomicAdd(dst + 1, t[1]);
            atomicAdd(dst + 2, t[2]); atomicAdd(dst + 3, t[3]);
            if (q == 0) atomicAdd(counts + seg, CHUNK);
        }
        return;
    }

    // ---- slow path: block crosses a segment boundary (<= 63 blocks) ----
    f4 acc = (f4)(0.f);
    int cur = sb[g];
    int cnt = 0;
    for (int i = 0; i < 64; ++i) {
        const int r = g + (i << 2);
        const f4 v = hv[(size_t)(base + r) * QV + q];
        const int s = sb[r];
        if (s != cur) {
            float* dst = seg_sum + cur * H + q * 4;
            atomicAdd(dst + 0, acc[0]); atomicAdd(dst + 1, acc[1]);
            atomicAdd(dst + 2, acc[2]); atomicAdd(dst + 3, acc[3]);
            if (q == 0) atomicAdd(counts + cur, cnt);
            acc = (f4)(0.f); cnt = 0; cur = s;
        }
        acc += v; ++cnt;
    }
    float* dst = seg_sum + cur * H + q * 4;
    atomicAdd(dst + 0, acc[0]); atomicAdd(dst + 1, acc[1]);
    atomicAdd(dst + 2, acc[2]); atomicAdd(dst + 3, acc[3]);
    if (q == 0) atomicAdd(counts + cur, cnt);
}

// ---------------------------------------------------------------------------
// k2: per-segment gated MLP. One block per segment, wave-per-output dot
// products, lane-split K, shfl butterfly reduce. W1/W2 L2-resident.
// ---------------------------------------------------------------------------
__global__ __launch_bounds__(512) void k_mlp(
    const float* __restrict__ seg_sum, const int* __restrict__ counts,
    const float* __restrict__ W1, const float* __restrict__ b1,
    const float* __restrict__ W2, const float* __restrict__ b2,
    float* __restrict__ gate)
{
    __shared__ float c[H];
    __shared__ float hd[H];
    const int s   = blockIdx.x;
    const int tid = threadIdx.x;

    const float cntf = fmaxf((float)counts[s], 1.0f);
    c[tid] = seg_sum[s * H + tid] / cntf;
    __syncthreads();

    const int w = tid >> 6;   // wave 0..7
    const int l = tid & 63;   // lane 0..63

    for (int jb = 0; jb < H / 8; ++jb) {
        const int j = jb * 8 + w;
        const float* __restrict__ wr = W1 + (size_t)j * H;
        float acc = 0.f;
        #pragma unroll
        for (int m = 0; m < H / 64; ++m)
            acc += c[m * 64 + l] * wr[m * 64 + l];
        #pragma unroll
        for (int off = 32; off > 0; off >>= 1)
            acc += __shfl_xor(acc, off, 64);
        if (l == 0) hd[j] = fmaxf(acc + b1[j], 0.f);
    }
    __syncthreads();

    for (int jb = 0; jb < H / 8; ++jb) {
        const int j = jb * 8 + w;
        const float* __restrict__ wr = W2 + (size_t)j * H;
        float acc = 0.f;
        #pragma unroll
        for (int m = 0; m < H / 64; ++m)
            acc += hd[m * 64 + l] * wr[m * 64 + l];
        #pragma unroll
        for (int off = 32; off > 0; off >>= 1)
            acc += __shfl_xor(acc, off, 64);
        if (l == 0) gate[s * H + j] = 1.0f / (1.0f + expf(-(acc + b2[j])));
    }
}

// ---------------------------------------------------------------------------
// k3: out[i][:] = h_V[i][:] * gate[batch_id[i]][:].
// REVERSED block order: k1 streamed h_V forward, so L3 holds the tail;
// consume it first (L3 hits), then miss on the first half whose evictions
// only kill lines we've already used. Plain loads (hit L3), NT stores
// (out is write-once — don't let it evict h_V).
// ---------------------------------------------------------------------------
__global__ __launch_bounds__(512) void k_gate(
    const f4* __restrict__ hv, const int* __restrict__ bid,
    const f4* __restrict__ gate, f4* __restrict__ out)
{
    __shared__ int sb[CHUNK];
    const int blk  = gridDim.x - 1 - blockIdx.x;   // reverse order
    const int base = blk * CHUNK;
    const int tid  = threadIdx.x;
    if (tid < CHUNK) sb[tid] = bid[base + tid];
    __syncthreads();

    const int g = tid >> 7;
    const int q = tid & 127;

    if (sb[0] == sb[CHUNK - 1]) {
        // ---- fast path ----
        const f4 gv = gate[(size_t)sb[0] * QV + q];
        const f4* p = hv  + (size_t)(base + g) * QV + q;
        f4*       o = out + (size_t)(base + g) * QV + q;
        for (int i = 0; i < 16; ++i) {
            const size_t off = (size_t)i * (16 * QV);
            const f4 v0 = p[off];
            const f4 v1 = p[off + 4 * QV];
            const f4 v2 = p[off + 8 * QV];
            const f4 v3 = p[off + 12 * QV];
            ntstore4(o + off,           v0 * gv);
            ntstore4(o + off + 4 * QV,  v1 * gv);
            ntstore4(o + off + 8 * QV,  v2 * gv);
            ntstore4(o + off + 12 * QV, v3 * gv);
        }
        return;
    }

    // ---- slow path ----
    int cur = sb[g];
    f4 gv = gate[(size_t)cur * QV + q];
    for (int i = 0; i < 64; ++i) {
        const int r = g + (i << 2);
        const f4 v = hv[(size_t)(base + r) * QV + q];
        const int s = sb[r];
        if (s != cur) { cur = s; gv = gate[(size_t)cur * QV + q]; }
        ntstore4(out + (size_t)(base + r) * QV + q, v * gv);
    }
}

extern "C" void kernel_launch(void* const* d_in, const int* in_sizes, int n_in,
                              void* d_out, int out_size, void* d_ws, size_t ws_size,
                              hipStream_t stream)
{
    const float* h_V      = (const float*)d_in[0];
    const int*   batch_id = (const int*)d_in[1];
    const float* W1       = (const float*)d_in[2];
    const float* b1       = (const float*)d_in[3];
    const float* W2       = (const float*)d_in[4];
    const float* b2       = (const float*)d_in[5];

    const int N = in_sizes[0] / H;   // 262144

    char*  ws      = (char*)d_ws;
    float* seg_sum = (float*)ws;                   // 64*512*4 = 131072 B
    int*   counts  = (int*)(ws + 131072);          // 64*4     = 256 B
    float* gate    = (float*)(ws + 131072 + 256);  // 64*512*4 = 131072 B

    hipMemsetAsync(d_ws, 0, 131072 + 256, stream);

    k_segsum<<<N / CHUNK, 512, 0, stream>>>(
        (const f4*)h_V, batch_id, seg_sum, counts);

    k_mlp<<<NSEG, 512, 0, stream>>>(seg_sum, counts, W1, b1, W2, b2, gate);

    k_gate<<<N / CHUNK, 512, 0, stream>>>(
        (const f4*)h_V, batch_id, (const f4*)gate, (f4*)d_out);
}